// Round 10
// baseline (120.036 us; speedup 1.0000x reference)
//
#include <hip/hip_runtime.h>

#define NTOK 4096
#define CH 64
#define LOG2E 1.4426950408889634f
#define QK_SCALE 0.42466090014400953f   // sqrt(0.125 * log2(e)) folded into both q and k

typedef __bf16 bf8 __attribute__((ext_vector_type(8)));
typedef __bf16 bf4 __attribute__((ext_vector_type(4)));
typedef _Float16 h8 __attribute__((ext_vector_type(8)));
typedef _Float16 h4 __attribute__((ext_vector_type(4)));
typedef float f4 __attribute__((ext_vector_type(4)));
typedef long lx2 __attribute__((ext_vector_type(2)));   // 16B vector load

__device__ __forceinline__ f4 mfma16(bf8 a, bf8 b, f4 c) {
    return __builtin_amdgcn_mfma_f32_16x16x32_bf16(a, b, c, 0, 0, 0);
}
__device__ __forceinline__ f4 mfma8(long a, long b, f4 c) {
    return __builtin_amdgcn_mfma_f32_16x16x32_fp8_fp8(a, b, c, 0, 0, 0);
}
__device__ __forceinline__ unsigned char to_fp8(float v) {
    return (unsigned char)(__builtin_amdgcn_cvt_pk_fp8_f32(v, v, 0, false) & 0xff);
}
// Schraudolph fast exp2: 2^x ~= int_as_float((int)(x*2^23 + (127-0.0438)*2^23)).
// 2 full-rate VALU ops (fma + cvt) vs v_exp_f32's quarter-rate slot. Max rel err +-3.0%,
// below the fp8-e4m3 quantization granularity (+-6% ULP) already applied to p; the
// denominator (ones-MFMA) uses the same quantized p, so common-mode error cancels.
__device__ __forceinline__ float fexp2(float x) {
    return __int_as_float((int)fmaf(x, 8388608.f, 1064985795.f));
}

// ---------------- fused pre-pass: blocks 0..3 = weight transpose; 4..515 = GN partials ----
__global__ __launch_bounds__(256) void pre_kernel(const float* __restrict__ wq,
                                                  const float* __restrict__ wk,
                                                  const float* __restrict__ wv,
                                                  const float* __restrict__ wp,
                                                  const float* __restrict__ x,
                                                  __bf16* __restrict__ wqt,
                                                  __bf16* __restrict__ wkt,
                                                  __bf16* __restrict__ wvt,
                                                  __bf16* __restrict__ wpt,
                                                  float* __restrict__ gpart) {
    int t = threadIdx.x;
    if (blockIdx.x < 4) {   // weight transpose + bf16 convert
        int m = blockIdx.x;
        const float* src = (m == 0) ? wq : (m == 1) ? wk : (m == 2) ? wv : wp;
        __bf16* dst      = (m == 0) ? wqt : (m == 1) ? wkt : (m == 2) ? wvt : wpt;
        __shared__ float s[64][65];
        for (int i = 0; i < 16; ++i) {
            int e = i * 256 + t;
            s[e >> 6][e & 63] = src[e];
        }
        __syncthreads();
        int o = t >> 2, seg = t & 3;
        for (int j = 0; j < 16; ++j) {
            int in = seg * 16 + j;
            dst[o * 64 + in] = (__bf16)s[in][o];
        }
        return;
    }
    // GN partial sums: 512 blocks = 8b x 64 slabs of 64 rows
    int bid = blockIdx.x - 4;
    int b = bid >> 6, slab = bid & 63;
    const float4* xb = (const float4*)(x + (size_t)(b * NTOK + slab * 64) * CH);
    float s = 0.f, ss = 0.f;
    for (int i = 0; i < 4; ++i) {
        int row = (t >> 4) + i * 16;
        float4 v = xb[row * 16 + (t & 15)];
        s  += v.x + v.y + v.z + v.w;
        ss += v.x * v.x + v.y * v.y + v.z * v.z + v.w * v.w;
    }
    __shared__ float ls[256], lss[256];
    ls[t] = s; lss[t] = ss;
    __syncthreads();
    if (t < 8) {
        float a = 0.f, aa = 0.f;
        for (int p = 0; p < 16; ++p) {
            a  += ls[p * 16 + 2 * t]  + ls[p * 16 + 2 * t + 1];
            aa += lss[p * 16 + 2 * t] + lss[p * 16 + 2 * t + 1];
        }
        gpart[((b * 64 + slab) * 8 + t) * 2 + 0] = a;
        gpart[((b * 64 + slab) * 8 + t) * 2 + 1] = aa;
    }
}

// ---------------- fused GN + QKV projection (grid 512, 64 rows/block) --------------------
// (unchanged from R6 — x fragments hoisted, in-register GN, packed fp8 Q/K/V writeout)
__global__ __launch_bounds__(256) void qkv_gn(const float* __restrict__ x,
                                              const float* __restrict__ gpart,
                                              const float* __restrict__ gamma,
                                              const float* __restrict__ beta,
                                              const __bf16* __restrict__ wqt,
                                              const __bf16* __restrict__ wkt,
                                              const __bf16* __restrict__ wvt,
                                              const float* __restrict__ bq,
                                              const float* __restrict__ bk,
                                              const float* __restrict__ bv,
                                              unsigned char* __restrict__ qp,
                                              unsigned char* __restrict__ kp,
                                              unsigned char* __restrict__ vp) {
    __shared__ __bf16 W[3][64][72];
    __shared__ _Float16 Vst[64][68];
    __shared__ unsigned char Qst[64][72];
    __shared__ unsigned char Kst[64][72];
    __shared__ float red[128];
    __shared__ float sstat[16];
    __shared__ float sg[64], sb2[64];
    int t = threadIdx.x;
    size_t rowbase = (size_t)blockIdx.x * 64;
    int b = (int)(rowbase >> 12), tokbase = (int)(rowbase & 4095);
    int lane = t & 63, wave = t >> 6, quad = lane >> 4, l15 = lane & 15;
    int row = wave * 16 + l15;

    // hoisted coalesced x fragment loads (row stride 256B; 4 lanes x 32B per row half)
    const float* xr = x + (rowbase + row) * 64;
    float4 xl0 = *(const float4*)(xr + quad * 8);
    float4 xl1 = *(const float4*)(xr + quad * 8 + 4);
    float4 xh0 = *(const float4*)(xr + 32 + quad * 8);
    float4 xh1 = *(const float4*)(xr + 32 + quad * 8 + 4);

    for (int m = 0; m < 3; ++m) {
        const __bf16* src = (m == 0) ? wqt : (m == 1) ? wkt : wvt;
        for (int i = 0; i < 2; ++i) {
            int e = i * 256 + t, rr = e >> 3, ch = e & 7;
            *(bf8*)&W[m][rr][ch * 8] = *(const bf8*)(src + rr * 64 + ch * 8);
        }
    }
    if (t < 64) { sg[t] = gamma[t]; sb2[t] = beta[t]; }
    if (t < 64) {
        int gi = t & 7, c = t >> 3;
        const float2* gp = (const float2*)gpart + (size_t)b * 512 + gi;
        float a = 0.f, aa = 0.f;
        for (int p = c * 8; p < c * 8 + 8; ++p) {
            float2 v = gp[(size_t)p * 8];
            a += v.x; aa += v.y;
        }
        red[t * 2] = a; red[t * 2 + 1] = aa;
    }
    __syncthreads();
    if (t < 8) {
        float a = 0.f, aa = 0.f;
        for (int c = 0; c < 8; ++c) {
            a  += red[(c * 8 + t) * 2];
            aa += red[(c * 8 + t) * 2 + 1];
        }
        float mean = a * (1.f / 32768.f);
        float var = aa * (1.f / 32768.f) - mean * mean;
        sstat[t * 2 + 0] = mean;
        sstat[t * 2 + 1] = rsqrtf(var + 1e-3f);
    }
    __syncthreads();

    // in-register GN -> bf16 A-fragments (channels quad*8.. = group quad; +32 = group 4+quad)
    bf8 a0, a1;
    {
        float mlo = sstat[quad * 2], rlo = sstat[quad * 2 + 1];
        float mhi = sstat[(4 + quad) * 2], rhi = sstat[(4 + quad) * 2 + 1];
        float xl[8] = {xl0.x, xl0.y, xl0.z, xl0.w, xl1.x, xl1.y, xl1.z, xl1.w};
        float xh[8] = {xh0.x, xh0.y, xh0.z, xh0.w, xh1.x, xh1.y, xh1.z, xh1.w};
#pragma unroll
        for (int j = 0; j < 8; ++j) {
            int c = quad * 8 + j;
            a0[j] = (__bf16)((xl[j] - mlo) * sg[c] * rlo + sb2[c]);
            a1[j] = (__bf16)((xh[j] - mhi) * sg[32 + c] * rhi + sb2[32 + c]);
        }
    }

    for (int m = 0; m < 3; ++m) {
        const float* bias = (m == 0) ? bq : (m == 1) ? bk : bv;
        float sc = (m == 2) ? 1.0f : QK_SCALE;
        for (int tt = 0; tt < 4; ++tt) {
            int col = l15 + 16 * tt;
            bf8 b0 = *(const bf8*)&W[m][col][quad * 8];
            bf8 b1 = *(const bf8*)&W[m][col][32 + quad * 8];
            f4 acc = {0.f, 0.f, 0.f, 0.f};
            acc = mfma16(a0, b0, acc);
            acc = mfma16(a1, b1, acc);
            float bb = bias[col];
            if (m == 2) {
                for (int r = 0; r < 4; ++r)
                    Vst[col][wave * 16 + quad * 4 + r] = (_Float16)(acc[r] + bb);
            } else if (m == 1) {
                for (int r = 0; r < 4; ++r)
                    Kst[wave * 16 + quad * 4 + r][col] = to_fp8((acc[r] + bb) * sc);
            } else {
                for (int r = 0; r < 4; ++r)
                    Qst[wave * 16 + quad * 4 + r][col] = to_fp8((acc[r] + bb) * sc);
            }
        }
    }
    __syncthreads();
    {   // packed fp8 K + Q writeout: wave = key16-tile index within block
        const unsigned char* krow = &Kst[wave * 16 + l15][0];
        lx2 kk; kk[0] = *(const long*)(krow + quad * 8);
        kk[1] = *(const long*)(krow + 32 + quad * 8);
        *(lx2*)(kp + (((size_t)b * 256 + (tokbase >> 4) + wave) * 64 + lane) * 16) = kk;
        const unsigned char* qrow = &Qst[wave * 16 + l15][0];
        lx2 qq; qq[0] = *(const long*)(qrow + quad * 8);
        qq[1] = *(const long*)(qrow + 32 + quad * 8);
        *(lx2*)(qp + (((size_t)b * 256 + (tokbase >> 4) + wave) * 64 + lane) * 16) = qq;
    }
    {   // packed fp8 V writeout (wave = td): two 32-key tiles per block
        int d = wave * 16 + l15;
        for (int kb = 0; kb < 2; ++kb) {
            h4 lo = *(const h4*)&Vst[d][kb * 32 + quad * 4];
            h4 hi = *(const h4*)&Vst[d][kb * 32 + 16 + quad * 4];
            int d0 = __builtin_amdgcn_cvt_pk_fp8_f32((float)lo[0], (float)lo[1], 0, false);
            d0     = __builtin_amdgcn_cvt_pk_fp8_f32((float)lo[2], (float)lo[3], d0, true);
            int d1 = __builtin_amdgcn_cvt_pk_fp8_f32((float)hi[0], (float)hi[1], 0, false);
            d1     = __builtin_amdgcn_cvt_pk_fp8_f32((float)hi[2], (float)hi[3], d1, true);
            long v8 = (long)(unsigned int)d0 | ((long)d1 << 32);
            int kt = (tokbase >> 5) + kb;
            *(long*)(vp + ((((size_t)b * 128 + kt) * 2 + (wave >> 1)) * 64 + lane) * 16
                        + (wave & 1) * 8) = v8;
        }
    }
}

// ---------------- fused attention + output projection + residual -------------------------
// R10 = R9 structure (q-tile 128, 8-wave block, 1 block/CU, 512 loads/CU, ping-pong)
// + Schraudolph fast-exp2 (fma+cvt, full-rate) replacing quarter-rate v_exp_f32.
// R9's null result vs R6 proved loads are no longer binding; exp-pipe (27us/CU) is.
__device__ __forceinline__ void load_kv(const unsigned char* kpw, const unsigned char* vpw,
                                        long kf[4], long vf[4]) {
    lx2 a = *(const lx2*)(kpw);
    lx2 b = *(const lx2*)(kpw + 1024);
    lx2 c = *(const lx2*)(vpw);
    lx2 d = *(const lx2*)(vpw + 1024);
    kf[0] = a[0]; kf[1] = a[1]; kf[2] = b[0]; kf[3] = b[1];
    vf[0] = c[0]; vf[1] = c[1]; vf[2] = d[0]; vf[3] = d[1];
}

__device__ __forceinline__ void compute32(const long kf[4], const long vf[4],
                                          const long aqlo[8], const long aqhi[8],
                                          long ones, f4 acc[8][4], f4 acc_li[8]) {
#pragma unroll
    for (int s = 0; s < 8; ++s) {
        f4 St0 = {0.f, 0.f, 0.f, 0.f};
        f4 St1 = {0.f, 0.f, 0.f, 0.f};
        St0 = mfma8(kf[0], aqlo[s], St0);
        St0 = mfma8(kf[1], aqhi[s], St0);
        St1 = mfma8(kf[2], aqlo[s], St1);
        St1 = mfma8(kf[3], aqhi[s], St1);
        float p00 = fexp2(St0[0]);
        float p01 = fexp2(St0[1]);
        float p02 = fexp2(St0[2]);
        float p03 = fexp2(St0[3]);
        float p10 = fexp2(St1[0]);
        float p11 = fexp2(St1[1]);
        float p12 = fexp2(St1[2]);
        float p13 = fexp2(St1[3]);
        int d0 = __builtin_amdgcn_cvt_pk_fp8_f32(p00, p01, 0, false);
        d0     = __builtin_amdgcn_cvt_pk_fp8_f32(p02, p03, d0, true);
        int d1 = __builtin_amdgcn_cvt_pk_fp8_f32(p10, p11, 0, false);
        d1     = __builtin_amdgcn_cvt_pk_fp8_f32(p12, p13, d1, true);
        long pf = (long)(unsigned int)d0 | ((long)d1 << 32);
        acc_li[s] = mfma8(ones, pf, acc_li[s]);             // row-sum of p (denominator)
        acc[s][0] = mfma8(vf[0], pf, acc[s][0]);
        acc[s][1] = mfma8(vf[1], pf, acc[s][1]);
        acc[s][2] = mfma8(vf[2], pf, acc[s][2]);
        acc[s][3] = mfma8(vf[3], pf, acc[s][3]);
    }
}

__global__ __launch_bounds__(512, 1) void attn_final(const unsigned char* __restrict__ qp,
                                                     const unsigned char* __restrict__ kp,
                                                     const unsigned char* __restrict__ vp,
                                                     const __bf16* __restrict__ wpt,
                                                     const float* __restrict__ bp,
                                                     const float* __restrict__ x,
                                                     const float* __restrict__ gpart,
                                                     const float* __restrict__ gamma,
                                                     const float* __restrict__ beta,
                                                     float* __restrict__ out) {
    __shared__ _Float16 Om[4][128][72];
    __shared__ float sS[4][128];
    __shared__ __bf16 Wl[64][72];
    __shared__ __bf16 Ol[128][72];
    __shared__ float red[128];
    __shared__ float sstat[16], sg[64], sb[64];

    int bid = blockIdx.x;
    int qt = bid >> 3, b = bid & 7;     // qt in 0..31, 128-row q-tiles
    int t = threadIdx.x, lane = t & 63, w = t >> 6, quad = lane >> 4, l15 = lane & 15;

    {   // Wl stage: 512 threads, one bf8 chunk each
        int row = t >> 3, ch = t & 7;
        *(bf8*)&Wl[row][ch * 8] = *(const bf8*)(wpt + row * 64 + ch * 8);
    }
    if (t >= 64 && t < 128) { int u = t - 64; sg[u] = gamma[u]; sb[u] = beta[u]; }
    if (t < 64) {
        int gi = t & 7, c = t >> 3;
        const float2* gp = (const float2*)gpart + (size_t)b * 512 + gi;
        float a = 0.f, aa = 0.f;
        for (int p = c * 8; p < c * 8 + 8; ++p) {
            float2 v = gp[(size_t)p * 8];
            a += v.x; aa += v.y;
        }
        red[t * 2] = a; red[t * 2 + 1] = aa;
    }

    // Q fragments: 8 x 16-row tiles (tiles qt*8 .. qt*8+7), same for all waves
    const unsigned char* qpb = qp + (((size_t)b * 256 + qt * 8) * 64 + lane) * 16;
    long aqlo[8], aqhi[8];
#pragma unroll
    for (int s = 0; s < 8; ++s) {
        lx2 qq = *(const lx2*)(qpb + (size_t)s * 1024);
        aqlo[s] = qq[0]; aqhi[s] = qq[1];
    }
    // wave w owns keys [w*512, w*512+512): K tiles w*32.., V kt32 chunks w*16..
    const unsigned char* kpw = kp + ((size_t)b * 256 + w * 32) * 1024 + lane * 16;
    const unsigned char* vpw = vp + ((size_t)b * 128 + w * 16) * 2048 + lane * 16;

    const long ones = 0x3838383838383838L;   // 8 x e4m3(1.0)

    f4 acc[8][4] = {};
    f4 acc_li[8] = {};

    // 2-deep ping-pong over 16 key-tiles (4 loads/iter)
    long kfA[4], kfB[4], vfA[4], vfB[4];
    load_kv(kpw, vpw, kfA, vfA);
    for (int it = 0; it < 16; it += 2) {
        load_kv(kpw + (size_t)(it + 1) * 2048, vpw + (size_t)(it + 1) * 2048, kfB, vfB);
        __builtin_amdgcn_s_setprio(1);
        compute32(kfA, vfA, aqlo, aqhi, ones, acc, acc_li);
        __builtin_amdgcn_s_setprio(0);
        if (it + 2 < 16)
            load_kv(kpw + (size_t)(it + 2) * 2048, vpw + (size_t)(it + 2) * 2048, kfA, vfA);
        __builtin_amdgcn_s_setprio(1);
        compute32(kfB, vfB, aqlo, aqhi, ones, acc, acc_li);
        __builtin_amdgcn_s_setprio(0);
    }

    // denominator per query (identical in all lanes of the quad-group already)
    float li[8];
#pragma unroll
    for (int s = 0; s < 8; ++s) li[s] = acc_li[s][0];

    // ---- 3-level pairwise merge tree (8 waves -> 1), 128 q-rows ----
    if (w >= 4) {   // level A: waves 4-7 deposit
        for (int s = 0; s < 8; ++s) {
            for (int td = 0; td < 4; ++td) {
                h4 o4;
                for (int r = 0; r < 4; ++r) o4[r] = (_Float16)acc[s][td][r];
                *(h4*)&Om[w - 4][s * 16 + l15][td * 16 + quad * 4] = o4;
            }
            if (quad == 0) sS[w - 4][s * 16 + l15] = li[s];
        }
    }
    __syncthreads();
    if (t < 8) {    // GN stats finalize (red visible now)
        float a = 0.f, aa = 0.f;
        for (int c = 0; c < 8; ++c) {
            a  += red[(c * 8 + t) * 2];
            aa += red[(c * 8 + t) * 2 + 1];
        }
        float mean = a * (1.f / 32768.f);
        float var = aa * (1.f / 32768.f) - mean * mean;
        sstat[t * 2 + 0] = mean;
        sstat[t * 2 + 1] = rsqrtf(var + 1e-3f);
    }
    if (w < 4) {    // level A absorb
        for (int s = 0; s < 8; ++s) {
            for (int td = 0; td < 4; ++td) {
                h4 o4 = *(const h4*)&Om[w][s * 16 + l15][td * 16 + quad * 4];
                for (int r = 0; r < 4; ++r) acc[s][td][r] += (float)o4[r];
            }
            li[s] += sS[w][s * 16 + l15];
        }
    }
    __syncthreads();
    if (w >= 2 && w < 4) {  // level B: waves 2,3 deposit
        for (int s = 0; s < 8; ++s) {
            for (int td = 0; td < 4; ++td) {
                h4 o4;
                for (int r = 0; r < 4; ++r) o4[r] = (_Float16)acc[s][td][r];
                *(h4*)&Om[w - 2][s * 16 + l15][td * 16 + quad * 4] = o4;
            }
            if (quad == 0) sS[w - 2][s * 16 + l15] = li[s];
        }
    }
    __syncthreads();
    if (w < 2) {    // level B absorb
        for (int s = 0; s < 8; ++s) {
            for (int td = 0; td < 4; ++td) {
                h4 o4 = *(const h4*)&Om[w][s * 16 + l15][td * 16 + quad * 4];
                for (int r = 0; r < 4; ++r) acc[s][td][r] += (float)o4[r];
            }
            li[s] += sS[w][s * 16 + l15];
        }
    }
    __syncthreads();
    if (w < 2) {    // level C: waves 0,1 deposit pair-sums
        for (int s = 0; s < 8; ++s) {
            for (int td = 0; td < 4; ++td) {
                h4 o4;
                for (int r = 0; r < 4; ++r) o4[r] = (_Float16)acc[s][td][r];
                *(h4*)&Om[w][s * 16 + l15][td * 16 + quad * 4] = o4;
            }
            if (quad == 0) sS[w][s * 16 + l15] = li[s];
        }
    }
    __syncthreads();
    {   // final combine + normalize into Ol (bf16): 512 threads = 128 rows x 4 col-chunks
        int qq = t >> 2, ds = (t & 3) * 16;
        float inv = 1.f / (sS[0][qq] + sS[1][qq]);
        h8 a0 = *(const h8*)&Om[0][qq][ds];
        h8 b0 = *(const h8*)&Om[0][qq][ds + 8];
        h8 a1 = *(const h8*)&Om[1][qq][ds];
        h8 b1 = *(const h8*)&Om[1][qq][ds + 8];
        bf8 olo, ohi;
        for (int j = 0; j < 8; ++j) {
            olo[j] = (__bf16)(((float)a0[j] + (float)a1[j]) * inv);
            ohi[j] = (__bf16)(((float)b0[j] + (float)b1[j]) * inv);
        }
        *(bf8*)&Ol[qq][ds] = olo;
        *(bf8*)&Ol[qq][ds + 8] = ohi;
    }
    __syncthreads();
    // epilogue: out = Ol @ wp^T + bp + GN(x); wave w: rows [w*16, w*16+16), all 4 col-tiles
    {
        size_t rowbase = ((size_t)b * NTOK + qt * 128) + w * 16;
        bf8 a0 = *(const bf8*)&Ol[w * 16 + l15][quad * 8];
        bf8 a1 = *(const bf8*)&Ol[w * 16 + l15][32 + quad * 8];
        for (int tt = 0; tt < 4; ++tt) {
            int col = l15 + 16 * tt;
            bf8 b0 = *(const bf8*)&Wl[col][quad * 8];
            bf8 b1 = *(const bf8*)&Wl[col][32 + quad * 8];
            f4 pacc = {0.f, 0.f, 0.f, 0.f};
            pacc = mfma16(a0, b0, pacc);
            pacc = mfma16(a1, b1, pacc);
            int grp = col >> 3;
            float mean = sstat[grp * 2], gs = sg[col] * sstat[grp * 2 + 1], bs = sb[col];
            float bias = bp[col];
            for (int r = 0; r < 4; ++r) {
                size_t gi = (rowbase + quad * 4 + r) * 64 + col;
                float h = (x[gi] - mean) * gs + bs;
                out[gi] = pacc[r] + bias + h;
            }
        }
    }
}

extern "C" void kernel_launch(void* const* d_in, const int* in_sizes, int n_in,
                              void* d_out, int out_size, void* d_ws, size_t ws_size,
                              hipStream_t stream) {
    const float* x     = (const float*)d_in[0];
    const float* gamma = (const float*)d_in[1];
    const float* beta  = (const float*)d_in[2];
    const float* wq    = (const float*)d_in[3];
    const float* bq    = (const float*)d_in[4];
    const float* wk    = (const float*)d_in[5];
    const float* bk    = (const float*)d_in[6];
    const float* wv    = (const float*)d_in[7];
    const float* bv    = (const float*)d_in[8];
    const float* wp    = (const float*)d_in[9];
    const float* bp    = (const float*)d_in[10];
    float* out = (float*)d_out;

    char* ws = (char*)d_ws;
    const size_t MB = 1024 * 1024;
    unsigned char* qpb = (unsigned char*)(ws);            // 2 MB fp8 Q packed tiles
    unsigned char* kpb = (unsigned char*)(ws + 2 * MB);   // 2 MB fp8 K packed tiles
    unsigned char* vpb = (unsigned char*)(ws + 4 * MB);   // 2 MB fp8 V packed chunks
    __bf16*   wqt  = (__bf16*)(ws + 12 * MB);
    __bf16*   wkt  = (__bf16*)(ws + 12 * MB + 8192);
    __bf16*   wvt  = (__bf16*)(ws + 12 * MB + 16384);
    __bf16*   wpt  = (__bf16*)(ws + 12 * MB + 24576);
    float*    gpart = (float*)(ws + 12 * MB + 32768);     // 32 KB

    pre_kernel<<<516, 256, 0, stream>>>(wq, wk, wv, wp, x, wqt, wkt, wvt, wpt, gpart);
    qkv_gn<<<512, 256, 0, stream>>>(x, gpart, gamma, beta, wqt, wkt, wvt, bq, bk, bv,
                                    qpb, kpb, vpb);
    attn_final<<<256, 512, 0, stream>>>(qpb, kpb, vpb, wpt, bp, x, gpart, gamma, beta, out);
}

// Round 11
// 119.768 us; speedup vs baseline: 1.0022x; 1.0022x over previous
//
#include <hip/hip_runtime.h>

#define NTOK 4096
#define CH 64
#define LOG2E 1.4426950408889634f
#define QK_SCALE 0.42466090014400953f   // sqrt(0.125 * log2(e)) folded into both q and k

typedef __bf16 bf8 __attribute__((ext_vector_type(8)));
typedef __bf16 bf4 __attribute__((ext_vector_type(4)));
typedef _Float16 h8 __attribute__((ext_vector_type(8)));
typedef _Float16 h4 __attribute__((ext_vector_type(4)));
typedef float f4 __attribute__((ext_vector_type(4)));
typedef float fx16 __attribute__((ext_vector_type(16)));
typedef int ix4 __attribute__((ext_vector_type(4)));
typedef int ix8 __attribute__((ext_vector_type(8)));
typedef long lx2 __attribute__((ext_vector_type(2)));   // 16B vector load

__device__ __forceinline__ f4 mfma16(bf8 a, bf8 b, f4 c) {
    return __builtin_amdgcn_mfma_f32_16x16x32_bf16(a, b, c, 0, 0, 0);
}
// MX-scaled fp8 32x32x64 (unit scales): 2.3x per-FLOP vs non-scaled fp8 (4686 vs 2047 TF).
// A: row=lane&31, k=(lane>>5)*32 + byte (32B/lane). B: col=lane&31, same k map.
// C/D: col=lane&31, row=(reg&3)+8*(reg>>2)+4*(lane>>5)  [guide-verified shape layout].
__device__ __forceinline__ fx16 mfma_mx(ix8 a, ix8 b, fx16 c) {
    return __builtin_amdgcn_mfma_scale_f32_32x32x64_f8f6f4(
        a, b, c, 0, 0, 0, 0x7F7F7F7F, 0, 0x7F7F7F7F);
}
__device__ __forceinline__ unsigned char to_fp8(float v) {
    return (unsigned char)(__builtin_amdgcn_cvt_pk_fp8_f32(v, v, 0, false) & 0xff);
}
// Schraudolph fast exp2 (fma + cvt, full-rate VALU)
__device__ __forceinline__ float fexp2(float x) {
    return __int_as_float((int)fmaf(x, 8388608.f, 1064985795.f));
}
__device__ __forceinline__ ix8 load32(const unsigned char* p) {
    ix4 lo = *(const ix4*)p;
    ix4 hi = *(const ix4*)(p + 16);
    ix8 r;
    r[0] = lo[0]; r[1] = lo[1]; r[2] = lo[2]; r[3] = lo[3];
    r[4] = hi[0]; r[5] = hi[1]; r[6] = hi[2]; r[7] = hi[3];
    return r;
}

// ---------------- fused pre-pass: blocks 0..3 = weight transpose; 4..515 = GN partials ----
__global__ __launch_bounds__(256) void pre_kernel(const float* __restrict__ wq,
                                                  const float* __restrict__ wk,
                                                  const float* __restrict__ wv,
                                                  const float* __restrict__ wp,
                                                  const float* __restrict__ x,
                                                  __bf16* __restrict__ wqt,
                                                  __bf16* __restrict__ wkt,
                                                  __bf16* __restrict__ wvt,
                                                  __bf16* __restrict__ wpt,
                                                  float* __restrict__ gpart) {
    int t = threadIdx.x;
    if (blockIdx.x < 4) {   // weight transpose + bf16 convert
        int m = blockIdx.x;
        const float* src = (m == 0) ? wq : (m == 1) ? wk : (m == 2) ? wv : wp;
        __bf16* dst      = (m == 0) ? wqt : (m == 1) ? wkt : (m == 2) ? wvt : wpt;
        __shared__ float s[64][65];
        for (int i = 0; i < 16; ++i) {
            int e = i * 256 + t;
            s[e >> 6][e & 63] = src[e];
        }
        __syncthreads();
        int o = t >> 2, seg = t & 3;
        for (int j = 0; j < 16; ++j) {
            int in = seg * 16 + j;
            dst[o * 64 + in] = (__bf16)s[in][o];
        }
        return;
    }
    // GN partial sums: 512 blocks = 8b x 64 slabs of 64 rows
    int bid = blockIdx.x - 4;
    int b = bid >> 6, slab = bid & 63;
    const float4* xb = (const float4*)(x + (size_t)(b * NTOK + slab * 64) * CH);
    float s = 0.f, ss = 0.f;
    for (int i = 0; i < 4; ++i) {
        int row = (t >> 4) + i * 16;
        float4 v = xb[row * 16 + (t & 15)];
        s  += v.x + v.y + v.z + v.w;
        ss += v.x * v.x + v.y * v.y + v.z * v.z + v.w * v.w;
    }
    __shared__ float ls[256], lss[256];
    ls[t] = s; lss[t] = ss;
    __syncthreads();
    if (t < 8) {
        float a = 0.f, aa = 0.f;
        for (int p = 0; p < 16; ++p) {
            a  += ls[p * 16 + 2 * t]  + ls[p * 16 + 2 * t + 1];
            aa += lss[p * 16 + 2 * t] + lss[p * 16 + 2 * t + 1];
        }
        gpart[((b * 64 + slab) * 8 + t) * 2 + 0] = a;
        gpart[((b * 64 + slab) * 8 + t) * 2 + 1] = aa;
    }
}

// ---------------- fused GN + QKV projection (grid 512, 64 rows/block) --------------------
// Outputs for the MX 32x32x64 attn:
//  qp/kp : [b][tile32 (128)][lane64][32B]  lane(row=l&31, h=l>>5): bytes = row's channels
//          [32h, 32h+32)  (both scaled by QK_SCALE)
//  vp    : [b][kt64 (64)][dt(2)][lane64][32B]  lane(d=dt*32+(l&31), h=l>>5): byte
//          eo=kb*16+e' holds V[key kb*32+(e'&3)+8*(e'>>2)+4h][d] -- the slot permutation
//          sigma matching the QK C-layout so PV contracts with no cross-lane ops.
__global__ __launch_bounds__(256) void qkv_gn(const float* __restrict__ x,
                                              const float* __restrict__ gpart,
                                              const float* __restrict__ gamma,
                                              const float* __restrict__ beta,
                                              const __bf16* __restrict__ wqt,
                                              const __bf16* __restrict__ wkt,
                                              const __bf16* __restrict__ wvt,
                                              const float* __restrict__ bq,
                                              const float* __restrict__ bk,
                                              const float* __restrict__ bv,
                                              unsigned char* __restrict__ qp,
                                              unsigned char* __restrict__ kp,
                                              unsigned char* __restrict__ vp) {
    __shared__ __bf16 W[3][64][72];
    __shared__ _Float16 Vst[64][68];
    __shared__ unsigned char Qst[64][80];
    __shared__ unsigned char Kst[64][80];
    __shared__ float red[128];
    __shared__ float sstat[16];
    __shared__ float sg[64], sb2[64];
    int t = threadIdx.x;
    size_t rowbase = (size_t)blockIdx.x * 64;
    int b = (int)(rowbase >> 12), tokbase = (int)(rowbase & 4095);
    int lane = t & 63, wave = t >> 6, quad = lane >> 4, l15 = lane & 15;
    int row = wave * 16 + l15;

    // hoisted coalesced x fragment loads
    const float* xr = x + (rowbase + row) * 64;
    float4 xl0 = *(const float4*)(xr + quad * 8);
    float4 xl1 = *(const float4*)(xr + quad * 8 + 4);
    float4 xh0 = *(const float4*)(xr + 32 + quad * 8);
    float4 xh1 = *(const float4*)(xr + 32 + quad * 8 + 4);

    for (int m = 0; m < 3; ++m) {
        const __bf16* src = (m == 0) ? wqt : (m == 1) ? wkt : wvt;
        for (int i = 0; i < 2; ++i) {
            int e = i * 256 + t, rr = e >> 3, ch = e & 7;
            *(bf8*)&W[m][rr][ch * 8] = *(const bf8*)(src + rr * 64 + ch * 8);
        }
    }
    if (t < 64) { sg[t] = gamma[t]; sb2[t] = beta[t]; }
    if (t < 64) {
        int gi = t & 7, c = t >> 3;
        const float2* gp = (const float2*)gpart + (size_t)b * 512 + gi;
        float a = 0.f, aa = 0.f;
        for (int p = c * 8; p < c * 8 + 8; ++p) {
            float2 v = gp[(size_t)p * 8];
            a += v.x; aa += v.y;
        }
        red[t * 2] = a; red[t * 2 + 1] = aa;
    }
    __syncthreads();
    if (t < 8) {
        float a = 0.f, aa = 0.f;
        for (int c = 0; c < 8; ++c) {
            a  += red[(c * 8 + t) * 2];
            aa += red[(c * 8 + t) * 2 + 1];
        }
        float mean = a * (1.f / 32768.f);
        float var = aa * (1.f / 32768.f) - mean * mean;
        sstat[t * 2 + 0] = mean;
        sstat[t * 2 + 1] = rsqrtf(var + 1e-3f);
    }
    __syncthreads();

    // in-register GN -> bf16 A-fragments
    bf8 a0, a1;
    {
        float mlo = sstat[quad * 2], rlo = sstat[quad * 2 + 1];
        float mhi = sstat[(4 + quad) * 2], rhi = sstat[(4 + quad) * 2 + 1];
        float xl[8] = {xl0.x, xl0.y, xl0.z, xl0.w, xl1.x, xl1.y, xl1.z, xl1.w};
        float xh[8] = {xh0.x, xh0.y, xh0.z, xh0.w, xh1.x, xh1.y, xh1.z, xh1.w};
#pragma unroll
        for (int j = 0; j < 8; ++j) {
            int c = quad * 8 + j;
            a0[j] = (__bf16)((xl[j] - mlo) * sg[c] * rlo + sb2[c]);
            a1[j] = (__bf16)((xh[j] - mhi) * sg[32 + c] * rhi + sb2[32 + c]);
        }
    }

    for (int m = 0; m < 3; ++m) {
        const float* bias = (m == 0) ? bq : (m == 1) ? bk : bv;
        float sc = (m == 2) ? 1.0f : QK_SCALE;
        for (int tt = 0; tt < 4; ++tt) {
            int col = l15 + 16 * tt;
            bf8 b0 = *(const bf8*)&W[m][col][quad * 8];
            bf8 b1 = *(const bf8*)&W[m][col][32 + quad * 8];
            f4 acc = {0.f, 0.f, 0.f, 0.f};
            acc = mfma16(a0, b0, acc);
            acc = mfma16(a1, b1, acc);
            float bb = bias[col];
            if (m == 2) {
                for (int r = 0; r < 4; ++r)
                    Vst[col][wave * 16 + quad * 4 + r] = (_Float16)(acc[r] + bb);
            } else if (m == 1) {
                for (int r = 0; r < 4; ++r)
                    Kst[wave * 16 + quad * 4 + r][col] = to_fp8((acc[r] + bb) * sc);
            } else {
                for (int r = 0; r < 4; ++r)
                    Qst[wave * 16 + quad * 4 + r][col] = to_fp8((acc[r] + bb) * sc);
            }
        }
    }
    __syncthreads();
    {   // packed Q/K writeout: thread t -> slot=t>>1 (tile,lane), 16B half hb=t&1
        int slot = t >> 1, hb = t & 1;
        int tile = slot >> 6, ln = slot & 63;
        int rr = tile * 32 + (ln & 31), h = ln >> 5;
        size_t dst = (((size_t)b * 128 + (tokbase >> 5) + tile) * 64 + ln) * 32 + hb * 16;
        *(lx2*)(kp + dst) = *(const lx2*)&Kst[rr][h * 32 + hb * 16];
        *(lx2*)(qp + dst) = *(const lx2*)&Qst[rr][h * 32 + hb * 16];
    }
    {   // slot-permuted fp8 V writeout: thread t -> dt=t>>7, ln=(t>>1)&63, kb=t&1
        int dt = t >> 7, ln = (t >> 1) & 63, kb = t & 1;
        int d = dt * 32 + (ln & 31), h = ln >> 5;
        unsigned int dw[4];
#pragma unroll
        for (int g = 0; g < 4; ++g) {
            int k0 = kb * 32 + 4 * h + 8 * g;
            int dd = __builtin_amdgcn_cvt_pk_fp8_f32((float)Vst[d][k0 + 0],
                                                     (float)Vst[d][k0 + 1], 0, false);
            dd     = __builtin_amdgcn_cvt_pk_fp8_f32((float)Vst[d][k0 + 2],
                                                     (float)Vst[d][k0 + 3], dd, true);
            dw[g] = (unsigned int)dd;
        }
        lx2 vv;
        vv[0] = (long)dw[0] | ((long)dw[1] << 32);
        vv[1] = (long)dw[2] | ((long)dw[3] << 32);
        *(lx2*)(vp + ((((size_t)b * 64 + (tokbase >> 6)) * 2 + dt) * 64 + ln) * 32
                   + kb * 16) = vv;
    }
}

// ---------------- fused attention + output projection + residual -------------------------
// R11: MX 32x32x64 inner loop. grid 256 = qt(32)*8 + b, block 512 = 8 waves, 1 block/CU
// (2 waves/SIMD), wave owns 512 keys = 8 iters x 64 keys. Per iter: 8 QK + 8 PV MFMA
// (2.3x per-FLOP vs fp8 16x16x32 -> MFMA term 18.6 -> 7.4us). li via VALU row-sum +
// one end shfl_xor(32). pf needs NO cross-lane: V is slot-permuted to match QK C-layout.
__global__ __launch_bounds__(512, 1) void attn_final(const unsigned char* __restrict__ qp,
                                                     const unsigned char* __restrict__ kp,
                                                     const unsigned char* __restrict__ vp,
                                                     const __bf16* __restrict__ wpt,
                                                     const float* __restrict__ bp,
                                                     const float* __restrict__ x,
                                                     const float* __restrict__ gpart,
                                                     const float* __restrict__ gamma,
                                                     const float* __restrict__ beta,
                                                     float* __restrict__ out) {
    __shared__ _Float16 Om[4][128][72];
    __shared__ float sS[4][128];
    __shared__ __bf16 Wl[64][72];
    __shared__ __bf16 Ol[128][72];
    __shared__ float red[128];
    __shared__ float sstat[16], sg[64], sb[64];

    int bid = blockIdx.x;
    int qt = bid >> 3, b = bid & 7;     // qt in 0..31, 128-row q-tiles
    int t = threadIdx.x, lane = t & 63, w = t >> 6, quad = lane >> 4, l15 = lane & 15;
    int l31 = lane & 31, hh = lane >> 5;

    {   // Wl stage
        int row = t >> 3, ch = t & 7;
        *(bf8*)&Wl[row][ch * 8] = *(const bf8*)(wpt + row * 64 + ch * 8);
    }
    if (t >= 64 && t < 128) { int u = t - 64; sg[u] = gamma[u]; sb[u] = beta[u]; }
    if (t < 64) {
        int gi = t & 7, c = t >> 3;
        const float2* gp = (const float2*)gpart + (size_t)b * 512 + gi;
        float a = 0.f, aa = 0.f;
        for (int p = c * 8; p < c * 8 + 8; ++p) {
            float2 v = gp[(size_t)p * 8];
            a += v.x; aa += v.y;
        }
        red[t * 2] = a; red[t * 2 + 1] = aa;
    }

    // Q fragments: 4 q-subtiles of 32 (B-operand layout == qp layout)
    const unsigned char* qpb = qp + (((size_t)b * 128 + qt * 4) * 64 + lane) * 32;
    ix8 Qf[4];
#pragma unroll
    for (int s = 0; s < 4; ++s) Qf[s] = load32(qpb + (size_t)s * 2048);
    // wave w owns kt32 tiles [w*16, w*16+16) and kt64 chunks [w*8, w*8+8)
    const unsigned char* kpw = kp + (((size_t)b * 128 + w * 16) * 64 + lane) * 32;
    const unsigned char* vpw = vp + (((size_t)b * 64 + w * 8) * 2 * 64 + lane) * 32;

    fx16 acc[2][4] = {};    // [dt][s]
    float li[4] = {0.f, 0.f, 0.f, 0.f};
    const fx16 fz = {};

    for (int it = 0; it < 8; ++it) {
        const unsigned char* kpt = kpw + (size_t)it * 4096;
        const unsigned char* vpt = vpw + (size_t)it * 4096;
        ix8 K0 = load32(kpt);
        ix8 K1 = load32(kpt + 2048);
        ix8 V0 = load32(vpt);
        ix8 V1 = load32(vpt + 2048);
        __builtin_amdgcn_s_setprio(1);
#pragma unroll
        for (int s = 0; s < 4; ++s) {
            fx16 St0 = mfma_mx(K0, Qf[s], fz);
            fx16 St1 = mfma_mx(K1, Qf[s], fz);
            ix8 pf;
#pragma unroll
            for (int g = 0; g < 4; ++g) {
                float p0 = fexp2(St0[4 * g + 0]);
                float p1 = fexp2(St0[4 * g + 1]);
                float p2 = fexp2(St0[4 * g + 2]);
                float p3 = fexp2(St0[4 * g + 3]);
                li[s] += (p0 + p1) + (p2 + p3);
                int dd = __builtin_amdgcn_cvt_pk_fp8_f32(p0, p1, 0, false);
                dd     = __builtin_amdgcn_cvt_pk_fp8_f32(p2, p3, dd, true);
                pf[g] = dd;
            }
#pragma unroll
            for (int g = 0; g < 4; ++g) {
                float p0 = fexp2(St1[4 * g + 0]);
                float p1 = fexp2(St1[4 * g + 1]);
                float p2 = fexp2(St1[4 * g + 2]);
                float p3 = fexp2(St1[4 * g + 3]);
                li[s] += (p0 + p1) + (p2 + p3);
                int dd = __builtin_amdgcn_cvt_pk_fp8_f32(p0, p1, 0, false);
                dd     = __builtin_amdgcn_cvt_pk_fp8_f32(p2, p3, dd, true);
                pf[4 + g] = dd;
            }
            acc[0][s] = mfma_mx(V0, pf, acc[0][s]);
            acc[1][s] = mfma_mx(V1, pf, acc[1][s]);
        }
        __builtin_amdgcn_s_setprio(0);
    }

    // complete denominators across lane halves (each half summed its own key slots)
#pragma unroll
    for (int s = 0; s < 4; ++s) li[s] += __shfl_xor(li[s], 32);

    // ---- 3-level pairwise merge tree (8 waves -> 1), 128 q-rows ----
    // acc[dt][s] reg 4g+r -> O[q = s*32+l31][d = dt*32 + 4*hh + 8g + r]
    if (w >= 4) {   // level A: waves 4-7 deposit
#pragma unroll
        for (int s = 0; s < 4; ++s) {
            int q = s * 32 + l31;
#pragma unroll
            for (int dt = 0; dt < 2; ++dt)
#pragma unroll
                for (int g = 0; g < 4; ++g) {
                    h4 o4;
#pragma unroll
                    for (int r = 0; r < 4; ++r) o4[r] = (_Float16)acc[dt][s][4 * g + r];
                    *(h4*)&Om[w - 4][q][dt * 32 + 4 * hh + 8 * g] = o4;
                }
            if (lane < 32) sS[w - 4][q] = li[s];
        }
    }
    __syncthreads();
    if (t < 8) {    // GN stats finalize
        float a = 0.f, aa = 0.f;
        for (int c = 0; c < 8; ++c) {
            a  += red[(c * 8 + t) * 2];
            aa += red[(c * 8 + t) * 2 + 1];
        }
        float mean = a * (1.f / 32768.f);
        float var = aa * (1.f / 32768.f) - mean * mean;
        sstat[t * 2 + 0] = mean;
        sstat[t * 2 + 1] = rsqrtf(var + 1e-3f);
    }
    if (w < 4) {    // level A absorb
#pragma unroll
        for (int s = 0; s < 4; ++s) {
            int q = s * 32 + l31;
#pragma unroll
            for (int dt = 0; dt < 2; ++dt)
#pragma unroll
                for (int g = 0; g < 4; ++g) {
                    h4 o4 = *(const h4*)&Om[w][q][dt * 32 + 4 * hh + 8 * g];
#pragma unroll
                    for (int r = 0; r < 4; ++r) acc[dt][s][4 * g + r] += (float)o4[r];
                }
            li[s] += sS[w][q];
        }
    }
    __syncthreads();
    if (w >= 2 && w < 4) {  // level B: waves 2,3 deposit
#pragma unroll
        for (int s = 0; s < 4; ++s) {
            int q = s * 32 + l31;
#pragma unroll
            for (int dt = 0; dt < 2; ++dt)
#pragma unroll
                for (int g = 0; g < 4; ++g) {
                    h4 o4;
#pragma unroll
                    for (int r = 0; r < 4; ++r) o4[r] = (_Float16)acc[dt][s][4 * g + r];
                    *(h4*)&Om[w - 2][q][dt * 32 + 4 * hh + 8 * g] = o4;
                }
            if (lane < 32) sS[w - 2][q] = li[s];
        }
    }
    __syncthreads();
    if (w < 2) {    // level B absorb
#pragma unroll
        for (int s = 0; s < 4; ++s) {
            int q = s * 32 + l31;
#pragma unroll
            for (int dt = 0; dt < 2; ++dt)
#pragma unroll
                for (int g = 0; g < 4; ++g) {
                    h4 o4 = *(const h4*)&Om[w][q][dt * 32 + 4 * hh + 8 * g];
#pragma unroll
                    for (int r = 0; r < 4; ++r) acc[dt][s][4 * g + r] += (float)o4[r];
                }
            li[s] += sS[w][q];
        }
    }
    __syncthreads();
    if (w < 2) {    // level C: waves 0,1 deposit pair-sums
#pragma unroll
        for (int s = 0; s < 4; ++s) {
            int q = s * 32 + l31;
#pragma unroll
            for (int dt = 0; dt < 2; ++dt)
#pragma unroll
                for (int g = 0; g < 4; ++g) {
                    h4 o4;
#pragma unroll
                    for (int r = 0; r < 4; ++r) o4[r] = (_Float16)acc[dt][s][4 * g + r];
                    *(h4*)&Om[w][q][dt * 32 + 4 * hh + 8 * g] = o4;
                }
            if (lane < 32) sS[w][q] = li[s];
        }
    }
    __syncthreads();
    {   // final combine + normalize into Ol (bf16): 512 threads = 128 rows x 4 col-chunks
        int qq = t >> 2, ds = (t & 3) * 16;
        float inv = 1.f / (sS[0][qq] + sS[1][qq]);
        h8 a0 = *(const h8*)&Om[0][qq][ds];
        h8 b0 = *(const h8*)&Om[0][qq][ds + 8];
        h8 a1 = *(const h8*)&Om[1][qq][ds];
        h8 b1 = *(const h8*)&Om[1][qq][ds + 8];
        bf8 olo, ohi;
        for (int j = 0; j < 8; ++j) {
            olo[j] = (__bf16)(((float)a0[j] + (float)a1[j]) * inv);
            ohi[j] = (__bf16)(((float)b0[j] + (float)b1[j]) * inv);
        }
        *(bf8*)&Ol[qq][ds] = olo;
        *(bf8*)&Ol[qq][ds + 8] = ohi;
    }
    __syncthreads();
    // epilogue: out = Ol @ wp^T + bp + GN(x); wave w: rows [w*16, w*16+16)
    {
        size_t rowbase = ((size_t)b * NTOK + qt * 128) + w * 16;
        bf8 a0 = *(const bf8*)&Ol[w * 16 + l15][quad * 8];
        bf8 a1 = *(const bf8*)&Ol[w * 16 + l15][32 + quad * 8];
        for (int tt = 0; tt < 4; ++tt) {
            int col = l15 + 16 * tt;
            bf8 b0 = *(const bf8*)&Wl[col][quad * 8];
            bf8 b1 = *(const bf8*)&Wl[col][32 + quad * 8];
            f4 pacc = {0.f, 0.f, 0.f, 0.f};
            pacc = mfma16(a0, b0, pacc);
            pacc = mfma16(a1, b1, pacc);
            int grp = col >> 3;
            float mean = sstat[grp * 2], gs = sg[col] * sstat[grp * 2 + 1], bs = sb[col];
            float bias = bp[col];
            for (int r = 0; r < 4; ++r) {
                size_t gi = (rowbase + quad * 4 + r) * 64 + col;
                float h = (x[gi] - mean) * gs + bs;
                out[gi] = pacc[r] + bias + h;
            }
        }
    }
}

extern "C" void kernel_launch(void* const* d_in, const int* in_sizes, int n_in,
                              void* d_out, int out_size, void* d_ws, size_t ws_size,
                              hipStream_t stream) {
    const float* x     = (const float*)d_in[0];
    const float* gamma = (const float*)d_in[1];
    const float* beta  = (const float*)d_in[2];
    const float* wq    = (const float*)d_in[3];
    const float* bq    = (const float*)d_in[4];
    const float* wk    = (const float*)d_in[5];
    const float* bk    = (const float*)d_in[6];
    const float* wv    = (const float*)d_in[7];
    const float* bv    = (const float*)d_in[8];
    const float* wp    = (const float*)d_in[9];
    const float* bp    = (const float*)d_in[10];
    float* out = (float*)d_out;

    char* ws = (char*)d_ws;
    const size_t MB = 1024 * 1024;
    unsigned char* qpb = (unsigned char*)(ws);            // 2 MB fp8 Q packed 32-tiles
    unsigned char* kpb = (unsigned char*)(ws + 2 * MB);   // 2 MB fp8 K packed 32-tiles
    unsigned char* vpb = (unsigned char*)(ws + 4 * MB);   // 2 MB fp8 V slot-permuted
    __bf16*   wqt  = (__bf16*)(ws + 12 * MB);
    __bf16*   wkt  = (__bf16*)(ws + 12 * MB + 8192);
    __bf16*   wvt  = (__bf16*)(ws + 12 * MB + 16384);
    __bf16*   wpt  = (__bf16*)(ws + 12 * MB + 24576);
    float*    gpart = (float*)(ws + 12 * MB + 32768);     // 32 KB

    pre_kernel<<<516, 256, 0, stream>>>(wq, wk, wv, wp, x, wqt, wkt, wvt, wpt, gpart);
    qkv_gn<<<512, 256, 0, stream>>>(x, gpart, gamma, beta, wqt, wkt, wvt, bq, bk, bv,
                                    qpb, kpb, vpb);
    attn_final<<<256, 512, 0, stream>>>(qpb, kpb, vpb, wpt, bp, x, gpart, gamma, beta, out);
}